// Round 7
// baseline (194.540 us; speedup 1.0000x reference)
//
#include <hip/hip_runtime.h>
#include <cstdint>
#include <cstddef>

// ConcreteLayer forward: out = x @ softmax_rows((W + gumbel(U))/T)
// Reformulation v2 (dependency-broken):
//   e[i,k]   = exp((W+G)/T)          (stored bf16, UNSCALED, transposed -> BT [OUT,IN])
//   dpart[t,i] = partial row sums of e over OUT-tile t   (non-atomic, exclusive writes)
//   bt_scale:  BT[k,i] *= 1/sum_t dpart[t,i]             (16 MB pass)
//   out = bf16(x) @ BT                                   (MFMA GEMM, split-K=2 atomics)
// B=4096, IN=4096, OUT=1024.
// ws: xb (bf16 x, 32MB) | bt (bf16 e^T [OUT,IN], 8MB) | dpart ([16][4096] f32, 256KB)
//
// GEMM history: 128x128/2blk-CU = 505 TF (R0); split-K4 (R1) regressed via 2x atomics;
// 2-phase dbuf (R2) neutral; 8-phase 256^2 (R4/R5) regressed 3x (within-phase
// read->wait->MFMA serialization); 128x64/4blk-CU (R6) = 557 TF, occupancy lever
// near-exhausted. GEMM FETCH=49MB ~= compulsory -> scheduling-bound, frozen as-is.
// R7: prep-side fix. total-gemm has been a constant ~126us across 4 prep structures
// while ideal prep traffic is ~30us. The cast/zero section used 20480 tiny blocks
// (24B/thread). Guideline 11: grid-stride with ~2048 blocks instead; trans tiles
// (1024 blocks, 40KB each) kept; numerics bit-identical.

#define TINYF 1.17549435082228750797e-38f
#define LN2F 0.69314718055994530942f
#define LOG2EF 1.44269504088896340736f

typedef unsigned short u16;
typedef __attribute__((ext_vector_type(8))) short bf16x8;
typedef __attribute__((ext_vector_type(4))) float f32x4;

__device__ __forceinline__ u16 f2bf(float f) {
  union { float f; uint32_t u; } v; v.f = f;
  uint32_t r = v.u + 0x7FFFu + ((v.u >> 16) & 1u);  // RNE
  return (u16)(r >> 16);
}
__device__ __forceinline__ float bf2f(u16 h) {
  union { float f; uint32_t u; } v; v.u = ((uint32_t)h) << 16;
  return v.f;
}

__device__ __forceinline__ float log2_hw(float x) { return __builtin_amdgcn_logf(x); }
__device__ __forceinline__ float exp2_hw(float x) { return __builtin_amdgcn_exp2f(x); }

// g = -ln(-ln(u)) = -ln2 * log2(ln2 * (-log2 u))
__device__ __forceinline__ float gumbel_fast(float u) {
  float t = -log2_hw(u);
  return -LN2F * log2_hw(t * LN2F);
}
__device__ __forceinline__ float exp_fast(float x) { return exp2_hw(x * LOG2EF); }

__device__ __forceinline__ void gld_lds16(const void* g, void* l) {
  __builtin_amdgcn_global_load_lds(
      (__attribute__((address_space(1))) void*)(g),
      (__attribute__((address_space(3))) void*)(l), 16, 0, 0);
}

// ---------------- kernel 1: fused prep ----------------
// blocks [0, 1024): 64x64 exp-transpose tiles of l -> BT (unscaled) + dpart sums
// blocks [1024, 1024+2048): grid-stride cast x->bf16 (8 float4/thread) then
//                           grid-stride zero of out (2 float4/thread)
#define NB_TRANS 1024
#define NB_STREAM 2048

__global__ void prep_kernel(const float* __restrict__ W, const float* __restrict__ U,
                            const float* __restrict__ Tp, const float4* __restrict__ x,
                            u16* __restrict__ BT, float* __restrict__ dpart,
                            ushort4* __restrict__ xb, float4* __restrict__ out,
                            int n4x, int n4o) {
  __shared__ float tile[64][65];
  const int bx = blockIdx.x;
  const int t = threadIdx.x;

  if (bx < NB_TRANS) {
    // ---- exp-transpose tile: k0 = IN-row tile (64 of them), n0 = OUT-col tile (16)
    const int k0 = (bx & 63) * 64, n0 = (bx >> 6) * 64;
    const float invT = 1.0f / Tp[0];
    {
      const int nn4 = (t & 15) * 4, kq = t >> 4;  // 16 rows per pass, float4 cols
#pragma unroll
      for (int r = 0; r < 4; ++r) {
        int kk = r * 16 + kq;
        size_t gi = (size_t)(k0 + kk) * 1024 + (n0 + nn4);
        float4 w = *(const float4*)&W[gi];
        float4 u = *(const float4*)&U[gi];
        float e0 = exp_fast((w.x + gumbel_fast(u.x * (1.0f - TINYF) + TINYF)) * invT);
        float e1 = exp_fast((w.y + gumbel_fast(u.y * (1.0f - TINYF) + TINYF)) * invT);
        float e2 = exp_fast((w.z + gumbel_fast(u.z * (1.0f - TINYF) + TINYF)) * invT);
        float e3 = exp_fast((w.w + gumbel_fast(u.w * (1.0f - TINYF) + TINYF)) * invT);
        tile[kk][nn4 + 0] = e0; tile[kk][nn4 + 1] = e1;
        tile[kk][nn4 + 2] = e2; tile[kk][nn4 + 3] = e3;
        // partial row sum over this thread's 4 cols; reduce across 16 lanes sharing kk
        float s = (e0 + e1) + (e2 + e3);
#pragma unroll
        for (int m = 8; m > 0; m >>= 1) s += __shfl_xor(s, m, 16);
        // exclusive (n-tile, row) slot: no atomics, no pre-zeroing needed
        if ((t & 15) == 0) dpart[(bx >> 6) * 4096 + k0 + kk] = s;
      }
    }
    __syncthreads();
    {
      const int kk4 = (t & 15) * 4, nq = t >> 4;
#pragma unroll
      for (int r = 0; r < 4; ++r) {
        int nn = r * 16 + nq;
        ushort4 o;
        o.x = f2bf(tile[kk4 + 0][nn]);
        o.y = f2bf(tile[kk4 + 1][nn]);
        o.z = f2bf(tile[kk4 + 2][nn]);
        o.w = f2bf(tile[kk4 + 3][nn]);
        *(ushort4*)&BT[(size_t)(n0 + nn) * 4096 + (k0 + kk4)] = o;
      }
    }
  } else {
    // ---- grid-stride streaming section (2048 blocks; meaty per-block work)
    const int base = (bx - NB_TRANS) * 256 + t;
    const int stride = NB_STREAM * 256;
    // x f32 -> bf16 (unscaled; 1/d lives on the BT side): n4x/stride = 8 iters
    for (int i = base; i < n4x; i += stride) {
      float4 v = x[i];
      ushort4 o;
      o.x = f2bf(v.x); o.y = f2bf(v.y); o.z = f2bf(v.z); o.w = f2bf(v.w);
      xb[i] = o;
    }
    // zero split-K accumulator: n4o/stride = 2 iters
    for (int j = base; j < n4o; j += stride) {
      out[j] = make_float4(0.f, 0.f, 0.f, 0.f);
    }
  }
}

// ---------------- kernel 2: BT[k,i] *= 1/d_i ----------------
__global__ void bt_scale_kernel(u16* __restrict__ BT, const float* __restrict__ dpart) {
  __shared__ float invd[128];
  const int c0 = blockIdx.x * 128;  // IN col tile (32)
  const int r0 = blockIdx.y * 128;  // OUT row tile (8)
  const int t = threadIdx.x;
  if (t < 128) {
    float s = 0.f;
#pragma unroll
    for (int p = 0; p < 16; ++p) s += dpart[p * 4096 + c0 + t];
    invd[t] = 1.0f / s;
  }
  __syncthreads();
  const int cv = (t & 15) * 8, rq = t >> 4;
  const float4 ia = *(const float4*)&invd[cv];
  const float4 ib = *(const float4*)&invd[cv + 4];
#pragma unroll
  for (int pass = 0; pass < 8; ++pass) {
    int row = r0 + pass * 16 + rq;
    size_t gi = (size_t)row * 4096 + c0 + cv;
    ushort4 a = *(ushort4*)&BT[gi];
    ushort4 b = *(ushort4*)&BT[gi + 4];
    ushort4 oa, ob;
    oa.x = f2bf(bf2f(a.x) * ia.x); oa.y = f2bf(bf2f(a.y) * ia.y);
    oa.z = f2bf(bf2f(a.z) * ia.z); oa.w = f2bf(bf2f(a.w) * ia.w);
    ob.x = f2bf(bf2f(b.x) * ib.x); ob.y = f2bf(bf2f(b.y) * ib.y);
    ob.z = f2bf(bf2f(b.z) * ib.z); ob.w = f2bf(bf2f(b.w) * ib.w);
    *(ushort4*)&BT[gi] = oa;
    *(ushort4*)&BT[gi + 4] = ob;
  }
}

// ---------------- kernel 3: GEMM 128x64 tile, TK=64, XOR-swizzled LDS, split-K=2 ----------------
// 4 waves (2x2 grid), per-wave output 64x32. acc = 4x2 f32x4 = 32 AGPR.
// LDS granule g of row r holds global 16B-granule (g ^ (r&7)) -> fragment ds_read_b128
// hits 8 distinct bank groups (2-way aliasing = free), staging stays lane-contiguous.
// LDS 24KB -> 6 blocks/CU cap; grid 1024 -> 4 blocks/CU offered. (R6: 61.7us, frozen.)
#define TM 128
#define TN 64
#define TK 64
#define SPLITK 2

__launch_bounds__(256)
__global__ void gemm_bt_kernel(const u16* __restrict__ A, const u16* __restrict__ BT,
                               float* __restrict__ C, int M, int N, int K) {
  __shared__ u16 As[TM * TK];  // 16 KB
  __shared__ u16 Bs[TN * TK];  // 8 KB

  const int tid = threadIdx.x;
  const int lane = tid & 63, w = tid >> 6;
  const int wm = w >> 1, wn = w & 1;           // 2x2 wave grid, 64x32 per wave
  const int m0 = blockIdx.x * TM, n0 = blockIdx.y * TN;
  const int quad = lane >> 4, r16 = lane & 15;
  const int srow = lane >> 3;                  // staging: row within 8-row chunk
  const int sg = (lane & 7) ^ srow;            // staging: swizzled 16B granule in row

  const int kz = blockIdx.z;                   // split-K = 2
  const int Kh = K >> 1;
  const u16* Ak = A + (size_t)kz * Kh;
  const u16* Bk = BT + (size_t)kz * Kh;

  f32x4 acc[4][2] = {};

  for (int kt = 0; kt < Kh; kt += TK) {
    __syncthreads();
#pragma unroll
    for (int c = 0; c < 4; ++c) {               // A: 16 chunks of 8 rows x 64 cols (1 KB)
      int chunk = w * 4 + c;
      gld_lds16(Ak + (size_t)(m0 + chunk * 8 + srow) * K + kt + sg * 8, (char*)As + chunk * 1024);
    }
#pragma unroll
    for (int c = 0; c < 2; ++c) {               // B: 8 chunks
      int chunk = w * 2 + c;
      gld_lds16(Bk + (size_t)(n0 + chunk * 8 + srow) * K + kt + sg * 8, (char*)Bs + chunk * 1024);
    }
    __syncthreads();

#pragma unroll
    for (int ss = 0; ss < 2; ++ss) {           // two K=32 sub-steps per staged TK=64
      bf16x8 aF[4], bF[2];
#pragma unroll
      for (int mi = 0; mi < 4; ++mi) {
        int row = wm * 64 + mi * 16 + r16;
        aF[mi] = *(const bf16x8*)((const char*)As + row * 128 + (((ss * 4 + quad) ^ (row & 7)) * 16));
      }
#pragma unroll
      for (int ni = 0; ni < 2; ++ni) {
        int row = wn * 32 + ni * 16 + r16;
        bF[ni] = *(const bf16x8*)((const char*)Bs + row * 128 + (((ss * 4 + quad) ^ (row & 7)) * 16));
      }
#pragma unroll
      for (int mi = 0; mi < 4; ++mi)
#pragma unroll
        for (int ni = 0; ni < 2; ++ni)
          acc[mi][ni] = __builtin_amdgcn_mfma_f32_16x16x32_bf16(aF[mi], bF[ni], acc[mi][ni], 0, 0, 0);
    }
  }

  // epilogue: C/D layout col = lane&15, row = quad*4 + reg
#pragma unroll
  for (int mi = 0; mi < 4; ++mi)
#pragma unroll
    for (int ni = 0; ni < 2; ++ni)
#pragma unroll
      for (int r = 0; r < 4; ++r) {
        int row = m0 + wm * 64 + mi * 16 + quad * 4 + r;
        int col = n0 + wn * 32 + ni * 16 + r16;
        atomicAdd(&C[(size_t)row * N + col], acc[mi][ni][r]);
      }
}

extern "C" void kernel_launch(void* const* d_in, const int* in_sizes, int n_in,
                              void* d_out, int out_size, void* d_ws, size_t ws_size,
                              hipStream_t stream) {
  const int M = 4096, K = 4096, N = 1024;  // B, IN, OUT
  const float* x = (const float*)d_in[0];
  const float* W = (const float*)d_in[1];
  const float* U = (const float*)d_in[2];
  const float* Tp = (const float*)d_in[3];
  float* out = (float*)d_out;

  char* ws = (char*)d_ws;
  u16* xb = (u16*)ws;                                          // 32 MB
  u16* bt = (u16*)(ws + (size_t)M * K * 2);                    // 8 MB
  float* dpart = (float*)(ws + (size_t)M * K * 2 + (size_t)N * K * 2);  // 256 KB

  const int n4x = M * K / 4, n4o = M * N / 4;
  prep_kernel<<<dim3(NB_TRANS + NB_STREAM), 256, 0, stream>>>(
      W, U, Tp, (const float4*)x, bt, dpart, (ushort4*)xb, (float4*)out, n4x, n4o);
  bt_scale_kernel<<<dim3(32, 8), 256, 0, stream>>>(bt, dpart);
  gemm_bt_kernel<<<dim3(M / TM, N / TN, SPLITK), 256, 0, stream>>>(xb, bt, out, M, N, K);
}